// Round 4
// baseline (53.306 us; speedup 1.0000x reference)
//
#include <hip/hip_runtime.h>
#include <math.h>

#define NB 64
#define V_FULL 6890
#define V_HAND 250
#define V_LOOP 20
#define N_FACES 500
#define NPTS 251      // V_HAND + 1 (appended loop-mean vertex)
#define KSPLIT 16     // lanes per point (face-loop split)
#define PCHUNK 16     // points per block
#define NCHUNK 16     // ceil(251/16)

// Branchless fast atan2: rcp-based division, Cephes range reduction
// (|z| <= tan(pi/8)) + degree-9 odd minimax poly. Max err ~3e-7 rad.
__device__ __forceinline__ float fast_atan2f(float y, float x) {
    const float PI   = 3.14159265358979f;
    const float PIO2 = 1.57079632679490f;
    const float PIO4 = 0.78539816339745f;
    float ay = __builtin_fabsf(y), ax = __builtin_fabsf(x);
    float mx = fmaxf(ax, ay), mn = fminf(ax, ay);
    float t  = mn * __builtin_amdgcn_rcpf(fmaxf(mx, 1e-38f));  // [0,1]
    bool  hi = t > 0.4142135624f;
    float z  = hi ? (t - 1.0f) * __builtin_amdgcn_rcpf(t + 1.0f) : t;
    float z2 = z * z;
    float p  = fmaf(8.05374449538e-2f, z2, -1.38776856032e-1f);
    p = fmaf(p, z2, 1.99777106478e-1f);
    p = fmaf(p, z2, -3.33329491539e-1f);
    float r = fmaf(z2 * z, p, z);
    r += hi ? PIO4 : 0.0f;
    if (ay > ax)  r = PIO2 - r;
    if (x < 0.0f) r = PI - r;
    return copysignf(r, y);
}

// Grid (NB, 2, NCHUNK). Block 256 = PCHUNK points x KSPLIT lanes.
// dir 0: points = left-hand verts, other = right, faces = faces_right
// dir 1: points = right-hand verts, other = left,  faces = faces_left
__global__ __launch_bounds__(256) void hand_pen_kernel(
    const float* __restrict__ verts,     // [NB][V_FULL][3]
    const int* __restrict__ inds_l,
    const int* __restrict__ inds_r,
    const int* __restrict__ loop_l,
    const int* __restrict__ loop_r,
    const int* __restrict__ faces_l,     // [N_FACES][3]
    const int* __restrict__ faces_r,
    float* __restrict__ partial)         // [NB][2][NCHUNK]
{
    const int b   = blockIdx.x;
    const int dir = blockIdx.y;
    const int z   = blockIdx.z;
    const int tid = threadIdx.x;
    const int lp  = tid >> 4;           // local point 0..15
    const int k   = tid & 15;           // split lane 0..15
    int p = z * PCHUNK + lp;
    const bool valid = (p < NPTS);
    if (!valid) p = NPTS - 1;           // clamp; contribution masked later

    __shared__ float  pts[NPTS][3];
    __shared__ float4 ov4[NPTS];        // other-hand verts (for setup + min-dist)
    __shared__ float4 tri0[N_FACES];    // per-face vertex 0 (point-independent!)
    __shared__ float4 tri1[N_FACES];
    __shared__ float4 tri2[N_FACES];
    __shared__ float  wave_part[4];

    const float* vb = verts + (size_t)b * V_FULL * 3;
    const int* pind  = (dir == 0) ? inds_l  : inds_r;
    const int* oind  = (dir == 0) ? inds_r  : inds_l;
    const int* ploop = (dir == 0) ? loop_l  : loop_r;
    const int* oloop = (dir == 0) ? loop_r  : loop_l;
    const int* fcs   = (dir == 0) ? faces_r : faces_l;

    // Phase 1: gather both hands' vertices
    for (int i = tid; i < V_HAND; i += 256) {
        int gp = pind[i];
        pts[i][0] = vb[gp * 3 + 0];
        pts[i][1] = vb[gp * 3 + 1];
        pts[i][2] = vb[gp * 3 + 2];
        int go = oind[i];
        ov4[i] = make_float4(vb[go * 3 + 0], vb[go * 3 + 1], vb[go * 3 + 2], 0.0f);
    }
    if (tid < 2) {
        const int* lpv = (tid == 0) ? ploop : oloop;
        float sx = 0.f, sy = 0.f, sz = 0.f;
        for (int i = 0; i < V_LOOP; ++i) {
            int gi = lpv[i];
            sx += vb[gi * 3 + 0];
            sy += vb[gi * 3 + 1];
            sz += vb[gi * 3 + 2];
        }
        const float inv = 1.0f / (float)V_LOOP;
        if (tid == 0) {
            pts[V_HAND][0] = sx * inv; pts[V_HAND][1] = sy * inv; pts[V_HAND][2] = sz * inv;
        } else {
            ov4[V_HAND] = make_float4(sx * inv, sy * inv, sz * inv, 0.0f);
        }
    }
    __syncthreads();

    // Phase 2: build per-face triangle vertex arrays (one random gather per
    // block instead of per point x face). Inner loop becomes affine-address.
    for (int i = tid; i < N_FACES; i += 256) {
        int i0 = fcs[3 * i + 0], i1 = fcs[3 * i + 1], i2 = fcs[3 * i + 2];
        tri0[i] = ov4[i0];
        tri1[i] = ov4[i1];
        tri2[i] = ov4[i2];
    }
    __syncthreads();

    const float px = pts[p][0], py = pts[p][1], pz = pts[p][2];

    // Partial winding sum over faces k, k+16, ...  (conflict-free b128 reads)
    float wsum = 0.0f;
    #pragma unroll 2
    for (int f = k; f < N_FACES; f += KSPLIT) {
        float4 va  = tri0[f];
        float4 vb4 = tri1[f];
        float4 vc  = tri2[f];
        float ax = va.x - px,  ay = va.y - py,  az = va.z - pz;
        float bx = vb4.x - px, by = vb4.y - py, bz = vb4.z - pz;
        float cx = vc.x - px,  cy = vc.y - py,  cz = vc.z - pz;

        float la = __builtin_amdgcn_sqrtf(ax * ax + ay * ay + az * az);
        float lb = __builtin_amdgcn_sqrtf(bx * bx + by * by + bz * bz);
        float lc = __builtin_amdgcn_sqrtf(cx * cx + cy * cy + cz * cz);

        float ux = by * cz - bz * cy;
        float uy = bz * cx - bx * cz;
        float uz = bx * cy - by * cx;
        float det = ax * ux + ay * uy + az * uz;

        float ab = ax * bx + ay * by + az * bz;
        float bc = bx * cx + by * cy + bz * cz;
        float ca = cx * ax + cy * ay + cz * az;

        float denom = la * lb * lc + ab * lc + bc * la + ca * lb;
        wsum += fast_atan2f(det, denom);
    }

    // Partial min-dist over verts k, k+16, ...
    float d2min = 1e30f;
    for (int j = k; j < NPTS; j += KSPLIT) {
        float4 v = ov4[j];
        float dx = v.x - px, dy = v.y - py, dz = v.z - pz;
        float d2 = dx * dx + dy * dy + dz * dz;
        d2min = fminf(d2min, d2);
    }

    // Reduce across the 16-lane group (wave-aligned)
    wsum += __shfl_xor(wsum, 1);
    wsum += __shfl_xor(wsum, 2);
    wsum += __shfl_xor(wsum, 4);
    wsum += __shfl_xor(wsum, 8);
    d2min = fminf(d2min, __shfl_xor(d2min, 1));
    d2min = fminf(d2min, __shfl_xor(d2min, 2));
    d2min = fminf(d2min, __shfl_xor(d2min, 4));
    d2min = fminf(d2min, __shfl_xor(d2min, 8));

    float contrib = 0.0f;
    if (k == 0 && valid && wsum > (float)M_PI)
        contrib = __builtin_amdgcn_sqrtf(d2min + 1e-12f);

    // Block reduction: wave64 shuffle then 4 partials in LDS
    for (int off = 32; off > 0; off >>= 1)
        contrib += __shfl_down(contrib, off);
    if ((tid & 63) == 0) wave_part[tid >> 6] = contrib;
    __syncthreads();
    if (tid == 0)
        partial[(b * 2 + dir) * NCHUNK + z] =
            wave_part[0] + wave_part[1] + wave_part[2] + wave_part[3];
}

__global__ void combine_kernel(const float* __restrict__ partial, float* __restrict__ out)
{
    int i = threadIdx.x;
    if (i < NB) {
        float s = 0.0f;
        for (int j = 0; j < 2 * NCHUNK; ++j)
            s += partial[i * 2 * NCHUNK + j];
        out[i] = s;
    }
}

extern "C" void kernel_launch(void* const* d_in, const int* in_sizes, int n_in,
                              void* d_out, int out_size, void* d_ws, size_t ws_size,
                              hipStream_t stream) {
    const float* verts  = (const float*)d_in[0];
    const int* inds_l   = (const int*)d_in[1];
    const int* inds_r   = (const int*)d_in[2];
    const int* loop_l   = (const int*)d_in[3];
    const int* loop_r   = (const int*)d_in[4];
    const int* faces_l  = (const int*)d_in[5];
    const int* faces_r  = (const int*)d_in[6];
    float* out = (float*)d_out;
    float* partial = (float*)d_ws;  // NB*2*NCHUNK floats

    hand_pen_kernel<<<dim3(NB, 2, NCHUNK), 256, 0, stream>>>(
        verts, inds_l, inds_r, loop_l, loop_r, faces_l, faces_r, partial);
    combine_kernel<<<1, 64, 0, stream>>>(partial, out);
}

// Round 5
// 52.553 us; speedup vs baseline: 1.0143x; 1.0143x over previous
//
#include <hip/hip_runtime.h>
#include <math.h>

#define NB 64
#define V_FULL 6890
#define V_HAND 250
#define V_LOOP 20
#define N_FACES 500
#define NPTS 251      // V_HAND + 1 (appended loop-mean vertex)
#define KSPLIT 16     // lanes per point (face-loop split)
#define PCHUNK 16     // points per block
#define NCHUNK 16     // ceil(251/16)

struct F3 { float x, y, z; };

// Branchless fast atan2: rcp-based division, Cephes range reduction
// (|z| <= tan(pi/8)) + degree-9 odd minimax poly. Max err ~3e-7 rad.
__device__ __forceinline__ float fast_atan2f(float y, float x) {
    const float PI   = 3.14159265358979f;
    const float PIO2 = 1.57079632679490f;
    const float PIO4 = 0.78539816339745f;
    float ay = __builtin_fabsf(y), ax = __builtin_fabsf(x);
    float mx = fmaxf(ax, ay), mn = fminf(ax, ay);
    float t  = mn * __builtin_amdgcn_rcpf(fmaxf(mx, 1e-38f));  // [0,1]
    bool  hi = t > 0.4142135624f;
    float z  = hi ? (t - 1.0f) * __builtin_amdgcn_rcpf(t + 1.0f) : t;
    float z2 = z * z;
    float p  = fmaf(8.05374449538e-2f, z2, -1.38776856032e-1f);
    p = fmaf(p, z2, 1.99777106478e-1f);
    p = fmaf(p, z2, -3.33329491539e-1f);
    float r = fmaf(z2 * z, p, z);
    r += hi ? PIO4 : 0.0f;
    if (ay > ax)  r = PIO2 - r;
    if (x < 0.0f) r = PI - r;
    return copysignf(r, y);
}

// Grid (NB, 2, NCHUNK). Block 256 = PCHUNK points x KSPLIT lanes.
// dir 0: points = left-hand verts, other = right, faces = faces_right
// dir 1: points = right-hand verts, other = left,  faces = faces_left
__global__ __launch_bounds__(256) void hand_pen_kernel(
    const float* __restrict__ verts,     // [NB][V_FULL][3]
    const int* __restrict__ inds_l,
    const int* __restrict__ inds_r,
    const int* __restrict__ loop_l,
    const int* __restrict__ loop_r,
    const int* __restrict__ faces_l,     // [N_FACES][3]
    const int* __restrict__ faces_r,
    float* __restrict__ partial)         // [NB][2][NCHUNK]
{
    const int b   = blockIdx.x;
    const int dir = blockIdx.y;
    const int z   = blockIdx.z;
    const int tid = threadIdx.x;
    const int lp  = tid >> 4;           // local point 0..15
    const int k   = tid & 15;           // split lane 0..15
    const int p   = z * PCHUNK + lp;
    const bool valid = (p < NPTS);

    __shared__ F3 sov[NPTS];            // other-hand verts   (3012 B)
    __shared__ F3 st0[N_FACES];         // face vertex 0      (6000 B)
    __shared__ F3 st1[N_FACES];
    __shared__ F3 st2[N_FACES];
    __shared__ F3 spts[PCHUNK];         // this block's query points (192 B)
    __shared__ float wave_part[4];

    const float* vb = verts + (size_t)b * V_FULL * 3;
    const int* pind  = (dir == 0) ? inds_l  : inds_r;
    const int* oind  = (dir == 0) ? inds_r  : inds_l;
    const int* ploop = (dir == 0) ? loop_l  : loop_r;
    const int* oloop = (dir == 0) ? loop_r  : loop_l;
    const int* fcs   = (dir == 0) ? faces_r : faces_l;

    // Phase 1: gather other-hand verts + this block's 16 query points
    for (int i = tid; i < V_HAND; i += 256) {
        int go = oind[i];
        sov[i].x = vb[go * 3 + 0];
        sov[i].y = vb[go * 3 + 1];
        sov[i].z = vb[go * 3 + 2];
    }
    if (tid == 0) {  // appended mean vertex of other hand
        float sx = 0.f, sy = 0.f, sz = 0.f;
        for (int i = 0; i < V_LOOP; ++i) {
            int gi = oloop[i];
            sx += vb[gi * 3 + 0]; sy += vb[gi * 3 + 1]; sz += vb[gi * 3 + 2];
        }
        const float inv = 1.0f / (float)V_LOOP;
        sov[V_HAND].x = sx * inv; sov[V_HAND].y = sy * inv; sov[V_HAND].z = sz * inv;
    }
    if (tid >= 32 && tid < 32 + PCHUNK) {
        int myp = z * PCHUNK + (tid - 32);
        F3 q = {0.f, 0.f, 0.f};
        if (myp < V_HAND) {
            int gp = pind[myp];
            q.x = vb[gp * 3 + 0]; q.y = vb[gp * 3 + 1]; q.z = vb[gp * 3 + 2];
        } else if (myp == V_HAND) {  // mean of this hand's loop verts
            float sx = 0.f, sy = 0.f, sz = 0.f;
            for (int i = 0; i < V_LOOP; ++i) {
                int gi = ploop[i];
                sx += vb[gi * 3 + 0]; sy += vb[gi * 3 + 1]; sz += vb[gi * 3 + 2];
            }
            const float inv = 1.0f / (float)V_LOOP;
            q.x = sx * inv; q.y = sy * inv; q.z = sz * inv;
        }
        spts[tid - 32] = q;
    }
    __syncthreads();

    // Phase 2: build per-face triangle vertex arrays (one random gather per
    // block instead of per point x face). Inner loop becomes affine-address.
    for (int i = tid; i < N_FACES; i += 256) {
        int i0 = fcs[3 * i + 0], i1 = fcs[3 * i + 1], i2 = fcs[3 * i + 2];
        st0[i] = sov[i0];
        st1[i] = sov[i1];
        st2[i] = sov[i2];
    }
    __syncthreads();

    const float px = spts[lp].x, py = spts[lp].y, pz = spts[lp].z;

    // Partial winding sum over faces k, k+16, ...  (~2-way banks = free)
    float wsum = 0.0f;
    #pragma unroll 2
    for (int f = k; f < N_FACES; f += KSPLIT) {
        F3 va = st0[f], vb3 = st1[f], vc = st2[f];
        float ax = va.x - px,  ay = va.y - py,  az = va.z - pz;
        float bx = vb3.x - px, by = vb3.y - py, bz = vb3.z - pz;
        float cx = vc.x - px,  cy = vc.y - py,  cz = vc.z - pz;

        float la = __builtin_amdgcn_sqrtf(ax * ax + ay * ay + az * az);
        float lb = __builtin_amdgcn_sqrtf(bx * bx + by * by + bz * bz);
        float lc = __builtin_amdgcn_sqrtf(cx * cx + cy * cy + cz * cz);

        float ux = by * cz - bz * cy;
        float uy = bz * cx - bx * cz;
        float uz = bx * cy - by * cx;
        float det = ax * ux + ay * uy + az * uz;

        float ab = ax * bx + ay * by + az * bz;
        float bc = bx * cx + by * cy + bz * cz;
        float ca = cx * ax + cy * ay + cz * az;

        float denom = fmaf(la, lb, ab) * lc + bc * la + ca * lb;
        wsum += fast_atan2f(det, denom);
    }

    // Partial min-dist over verts k, k+16, ...
    float d2min = 1e30f;
    for (int j = k; j < NPTS; j += KSPLIT) {
        F3 v = sov[j];
        float dx = v.x - px, dy = v.y - py, dz = v.z - pz;
        float d2 = dx * dx + dy * dy + dz * dz;
        d2min = fminf(d2min, d2);
    }

    // Reduce across the 16-lane group (wave-aligned)
    wsum += __shfl_xor(wsum, 1);
    wsum += __shfl_xor(wsum, 2);
    wsum += __shfl_xor(wsum, 4);
    wsum += __shfl_xor(wsum, 8);
    d2min = fminf(d2min, __shfl_xor(d2min, 1));
    d2min = fminf(d2min, __shfl_xor(d2min, 2));
    d2min = fminf(d2min, __shfl_xor(d2min, 4));
    d2min = fminf(d2min, __shfl_xor(d2min, 8));

    float contrib = 0.0f;
    if (k == 0 && valid && wsum > (float)M_PI)
        contrib = __builtin_amdgcn_sqrtf(d2min + 1e-12f);

    // Block reduction: wave64 shuffle then 4 partials in LDS
    for (int off = 32; off > 0; off >>= 1)
        contrib += __shfl_down(contrib, off);
    if ((tid & 63) == 0) wave_part[tid >> 6] = contrib;
    __syncthreads();
    if (tid == 0)
        partial[(b * 2 + dir) * NCHUNK + z] =
            wave_part[0] + wave_part[1] + wave_part[2] + wave_part[3];
}

__global__ void combine_kernel(const float* __restrict__ partial, float* __restrict__ out)
{
    int i = threadIdx.x;
    if (i < NB) {
        float s = 0.0f;
        for (int j = 0; j < 2 * NCHUNK; ++j)
            s += partial[i * 2 * NCHUNK + j];
        out[i] = s;
    }
}

extern "C" void kernel_launch(void* const* d_in, const int* in_sizes, int n_in,
                              void* d_out, int out_size, void* d_ws, size_t ws_size,
                              hipStream_t stream) {
    const float* verts  = (const float*)d_in[0];
    const int* inds_l   = (const int*)d_in[1];
    const int* inds_r   = (const int*)d_in[2];
    const int* loop_l   = (const int*)d_in[3];
    const int* loop_r   = (const int*)d_in[4];
    const int* faces_l  = (const int*)d_in[5];
    const int* faces_r  = (const int*)d_in[6];
    float* out = (float*)d_out;
    float* partial = (float*)d_ws;  // NB*2*NCHUNK floats

    hand_pen_kernel<<<dim3(NB, 2, NCHUNK), 256, 0, stream>>>(
        verts, inds_l, inds_r, loop_l, loop_r, faces_l, faces_r, partial);
    combine_kernel<<<1, 64, 0, stream>>>(partial, out);
}

// Round 6
// 51.091 us; speedup vs baseline: 1.0433x; 1.0286x over previous
//
#include <hip/hip_runtime.h>
#include <math.h>

#define NB 64
#define V_FULL 6890
#define V_HAND 250
#define V_LOOP 20
#define N_FACES 500
#define FPAD 512      // faces padded with degenerate (v0,v0,v0) -> omega = 0
#define NPTS 251      // V_HAND + 1 (appended loop-mean vertex)
#define NPTS_PAD 256  // min-dist pad (duplicates of vertex 0)
#define KSPLIT 8      // lanes per point (face-loop split)
#define PCHUNK 32     // points per block
#define NCHUNK 8      // 256 / PCHUNK

struct F3 { float x, y, z; };

// Branchless fast atan2. Range split decided BEFORE division (one rcp):
// hi <=> mn/mx > tan(pi/8) <=> mn > tan(pi/8)*mx. Poly max err ~3e-7 rad.
__device__ __forceinline__ float fast_atan2f(float y, float x) {
    const float PI   = 3.14159265358979f;
    const float PIO2 = 1.57079632679490f;
    const float PIO4 = 0.78539816339745f;
    float ay = __builtin_fabsf(y), ax = __builtin_fabsf(x);
    float mx = fmaxf(ax, ay), mn = fminf(ax, ay);
    bool  hi = mn > 0.4142135624f * mx;
    float num = hi ? (mn - mx) : mn;
    float den = hi ? (mn + mx) : mx;
    float z  = num * __builtin_amdgcn_rcpf(fmaxf(den, 1e-38f));
    float z2 = z * z;
    float p  = fmaf(8.05374449538e-2f, z2, -1.38776856032e-1f);
    p = fmaf(p, z2, 1.99777106478e-1f);
    p = fmaf(p, z2, -3.33329491539e-1f);
    float r = fmaf(z2 * z, p, z);
    r += hi ? PIO4 : 0.0f;
    if (ay > ax)  r = PIO2 - r;
    if (x < 0.0f) r = PI - r;
    return copysignf(r, y);
}

// Grid (NB, 2, NCHUNK). Block 256 = PCHUNK points x KSPLIT lanes.
__global__ __launch_bounds__(256) void hand_pen_kernel(
    const float* __restrict__ verts,     // [NB][V_FULL][3]
    const int* __restrict__ inds_l,
    const int* __restrict__ inds_r,
    const int* __restrict__ loop_l,
    const int* __restrict__ loop_r,
    const int* __restrict__ faces_l,     // [N_FACES][3]
    const int* __restrict__ faces_r,
    float* __restrict__ partial)         // [NB][2][NCHUNK]
{
    const int b   = blockIdx.x;
    const int dir = blockIdx.y;
    const int z   = blockIdx.z;
    const int tid = threadIdx.x;
    const int lp  = tid >> 3;           // local point 0..31
    const int k   = tid & 7;            // split lane 0..7
    const int p   = z * PCHUNK + lp;    // 0..255
    const bool valid = (p < NPTS);

    __shared__ F3     sov[NPTS_PAD];    // other-hand verts (3072 B)
    __shared__ float4 st0[FPAD];        // face vertex 0 (8192 B) - b128 affine
    __shared__ float4 st1[FPAD];
    __shared__ float4 st2[FPAD];
    __shared__ F3     spts[PCHUNK];     // this block's query points
    __shared__ float  wave_part[4];

    const float* vb = verts + (size_t)b * V_FULL * 3;
    const int* pind  = (dir == 0) ? inds_l  : inds_r;
    const int* oind  = (dir == 0) ? inds_r  : inds_l;
    const int* ploop = (dir == 0) ? loop_l  : loop_r;
    const int* oloop = (dir == 0) ? loop_r  : loop_l;
    const int* fcs   = (dir == 0) ? faces_r : faces_l;

    // Phase 1: gather other-hand verts (+pad) and this block's 32 points
    {
        int i = tid;  // 256 threads cover NPTS_PAD in one pass
        int go = (i < V_HAND) ? oind[i] : oind[0];   // pad = vertex 0 copy
        F3 v;
        v.x = vb[go * 3 + 0]; v.y = vb[go * 3 + 1]; v.z = vb[go * 3 + 2];
        if (i != V_HAND) sov[i] = v;                 // slot 250 = mean, below
    }
    if (tid == 0) {  // appended mean vertex of other hand
        float sx = 0.f, sy = 0.f, sz = 0.f;
        for (int i = 0; i < V_LOOP; ++i) {
            int gi = oloop[i];
            sx += vb[gi * 3 + 0]; sy += vb[gi * 3 + 1]; sz += vb[gi * 3 + 2];
        }
        const float inv = 1.0f / (float)V_LOOP;
        sov[V_HAND].x = sx * inv; sov[V_HAND].y = sy * inv; sov[V_HAND].z = sz * inv;
    }
    if (tid >= 64 && tid < 64 + PCHUNK) {
        int myp = z * PCHUNK + (tid - 64);
        F3 q = {0.f, 0.f, 0.f};
        if (myp < V_HAND) {
            int gp = pind[myp];
            q.x = vb[gp * 3 + 0]; q.y = vb[gp * 3 + 1]; q.z = vb[gp * 3 + 2];
        } else if (myp == V_HAND) {
            float sx = 0.f, sy = 0.f, sz = 0.f;
            for (int i = 0; i < V_LOOP; ++i) {
                int gi = ploop[i];
                sx += vb[gi * 3 + 0]; sy += vb[gi * 3 + 1]; sz += vb[gi * 3 + 2];
            }
            const float inv = 1.0f / (float)V_LOOP;
            q.x = sx * inv; q.y = sy * inv; q.z = sz * inv;
        }
        spts[tid - 64] = q;
    }
    __syncthreads();

    // Phase 2: build per-face float4 triangle arrays (random gather once per
    // block; main loop then reads affine b128). Pad faces are degenerate
    // (v,v,v): det=0, denom>0 -> contributes exactly 0.
    for (int i = tid; i < FPAD; i += 256) {
        float4 v0, v1, v2;
        if (i < N_FACES) {
            int i0 = fcs[3 * i + 0], i1 = fcs[3 * i + 1], i2 = fcs[3 * i + 2];
            F3 a = sov[i0], bq = sov[i1], c = sov[i2];
            v0 = make_float4(a.x, a.y, a.z, 0.f);
            v1 = make_float4(bq.x, bq.y, bq.z, 0.f);
            v2 = make_float4(c.x, c.y, c.z, 0.f);
        } else {
            F3 a = sov[0];
            v0 = v1 = v2 = make_float4(a.x, a.y, a.z, 0.f);
        }
        st0[i] = v0; st1[i] = v1; st2[i] = v2;
    }
    __syncthreads();

    const float px = spts[lp].x, py = spts[lp].y, pz = spts[lp].z;

    // Winding partial sum: uniform 64 iterations, 3x ds_read_b128 per face
    float wsum = 0.0f;
    #pragma unroll 2
    for (int f = k; f < FPAD; f += KSPLIT) {
        float4 va  = st0[f];
        float4 vb4 = st1[f];
        float4 vc  = st2[f];
        float ax = va.x - px,  ay = va.y - py,  az = va.z - pz;
        float bx = vb4.x - px, by = vb4.y - py, bz = vb4.z - pz;
        float cx = vc.x - px,  cy = vc.y - py,  cz = vc.z - pz;

        float la = __builtin_amdgcn_sqrtf(ax * ax + ay * ay + az * az);
        float lb = __builtin_amdgcn_sqrtf(bx * bx + by * by + bz * bz);
        float lc = __builtin_amdgcn_sqrtf(cx * cx + cy * cy + cz * cz);

        float ux = by * cz - bz * cy;
        float uy = bz * cx - bx * cz;
        float uz = bx * cy - by * cx;
        float det = ax * ux + ay * uy + az * uz;

        float ab = ax * bx + ay * by + az * bz;
        float bc = bx * cx + by * cy + bz * cz;
        float ca = cx * ax + cy * ay + cz * az;

        float denom = fmaf(la, lb, ab) * lc + bc * la + ca * lb;
        wsum += fast_atan2f(det, denom);
    }

    // Min-dist partial: uniform 32 iterations
    float d2min = 1e30f;
    for (int j = k; j < NPTS_PAD; j += KSPLIT) {
        F3 v = sov[j];
        float dx = v.x - px, dy = v.y - py, dz = v.z - pz;
        float d2 = dx * dx + dy * dy + dz * dz;
        d2min = fminf(d2min, d2);
    }

    // Reduce across the 8-lane group (wave-aligned)
    wsum += __shfl_xor(wsum, 1);
    wsum += __shfl_xor(wsum, 2);
    wsum += __shfl_xor(wsum, 4);
    d2min = fminf(d2min, __shfl_xor(d2min, 1));
    d2min = fminf(d2min, __shfl_xor(d2min, 2));
    d2min = fminf(d2min, __shfl_xor(d2min, 4));

    float contrib = 0.0f;
    if (k == 0 && valid && wsum > (float)M_PI)
        contrib = __builtin_amdgcn_sqrtf(d2min + 1e-12f);

    // Block reduction: wave64 shuffle then 4 partials in LDS
    for (int off = 32; off > 0; off >>= 1)
        contrib += __shfl_down(contrib, off);
    if ((tid & 63) == 0) wave_part[tid >> 6] = contrib;
    __syncthreads();
    if (tid == 0)
        partial[(b * 2 + dir) * NCHUNK + z] =
            wave_part[0] + wave_part[1] + wave_part[2] + wave_part[3];
}

__global__ void combine_kernel(const float* __restrict__ partial, float* __restrict__ out)
{
    int i = threadIdx.x;
    if (i < NB) {
        float s = 0.0f;
        for (int j = 0; j < 2 * NCHUNK; ++j)
            s += partial[i * 2 * NCHUNK + j];
        out[i] = s;
    }
}

extern "C" void kernel_launch(void* const* d_in, const int* in_sizes, int n_in,
                              void* d_out, int out_size, void* d_ws, size_t ws_size,
                              hipStream_t stream) {
    const float* verts  = (const float*)d_in[0];
    const int* inds_l   = (const int*)d_in[1];
    const int* inds_r   = (const int*)d_in[2];
    const int* loop_l   = (const int*)d_in[3];
    const int* loop_r   = (const int*)d_in[4];
    const int* faces_l  = (const int*)d_in[5];
    const int* faces_r  = (const int*)d_in[6];
    float* out = (float*)d_out;
    float* partial = (float*)d_ws;  // NB*2*NCHUNK floats

    hand_pen_kernel<<<dim3(NB, 2, NCHUNK), 256, 0, stream>>>(
        verts, inds_l, inds_r, loop_l, loop_r, faces_l, faces_r, partial);
    combine_kernel<<<1, 64, 0, stream>>>(partial, out);
}

// Round 7
// 40.742 us; speedup vs baseline: 1.3084x; 1.2540x over previous
//
#include <hip/hip_runtime.h>
#include <math.h>

#define NB 64
#define V_FULL 6890
#define V_HAND 250
#define V_LOOP 20
#define N_FACES 500
#define FPAD 512      // faces padded with degenerate (v0,v0,v0) -> omega = 0
#define NPTS 251      // V_HAND + 1 (appended loop-mean vertex)
#define NPTS_PAD 256  // min-dist pad (duplicates of vertex 0)
#define KSPLIT 16     // lanes per point-pair (face-loop split)
#define PCHUNK 32     // points per block (2 per thread)
#define NCHUNK 8      // 256 / PCHUNK

struct F3 { float x, y, z; };

// Branchless fast atan2. Range split decided BEFORE division (one rcp):
// hi <=> mn/mx > tan(pi/8). Poly max err ~3e-7 rad. atan2(0,0) -> 0.
__device__ __forceinline__ float fast_atan2f(float y, float x) {
    const float PI   = 3.14159265358979f;
    const float PIO2 = 1.57079632679490f;
    const float PIO4 = 0.78539816339745f;
    float ay = __builtin_fabsf(y), ax = __builtin_fabsf(x);
    float mx = fmaxf(ax, ay), mn = fminf(ax, ay);
    bool  hi = mn > 0.4142135624f * mx;
    float num = hi ? (mn - mx) : mn;
    float den = hi ? (mn + mx) : mx;
    float z  = num * __builtin_amdgcn_rcpf(fmaxf(den, 1e-38f));
    float z2 = z * z;
    float p  = fmaf(8.05374449538e-2f, z2, -1.38776856032e-1f);
    p = fmaf(p, z2, 1.99777106478e-1f);
    p = fmaf(p, z2, -3.33329491539e-1f);
    float r = fmaf(z2 * z, p, z);
    r += hi ? PIO4 : 0.0f;
    if (ay > ax)  r = PIO2 - r;
    if (x < 0.0f) r = PI - r;
    return copysignf(r, y);
}

// Solid-angle contribution of one triangle (va,vb,vc) seen from point p.
__device__ __forceinline__ float tri_omega(float4 va, float4 vb4, float4 vc,
                                           float px, float py, float pz) {
    float ax = va.x - px,  ay = va.y - py,  az = va.z - pz;
    float bx = vb4.x - px, by = vb4.y - py, bz = vb4.z - pz;
    float cx = vc.x - px,  cy = vc.y - py,  cz = vc.z - pz;

    float la = __builtin_amdgcn_sqrtf(ax * ax + ay * ay + az * az);
    float lb = __builtin_amdgcn_sqrtf(bx * bx + by * by + bz * bz);
    float lc = __builtin_amdgcn_sqrtf(cx * cx + cy * cy + cz * cz);

    float ux = by * cz - bz * cy;
    float uy = bz * cx - bx * cz;
    float uz = bx * cy - by * cx;
    float det = ax * ux + ay * uy + az * uz;

    float ab = ax * bx + ay * by + az * bz;
    float bc = bx * cx + by * cy + bz * cz;
    float ca = cx * ax + cy * ay + cz * az;

    float denom = fmaf(la, lb, ab) * lc + bc * la + ca * lb;
    return fast_atan2f(det, denom);
}

// Grid (NB, 2, NCHUNK). Block 256 = 16 point-pairs x KSPLIT lanes.
// Each thread processes points p0 = z*32+lp and p1 = p0+16 (ILP-2, shared
// face loads).
__global__ __launch_bounds__(256) void hand_pen_kernel(
    const float* __restrict__ verts,     // [NB][V_FULL][3]
    const int* __restrict__ inds_l,
    const int* __restrict__ inds_r,
    const int* __restrict__ loop_l,
    const int* __restrict__ loop_r,
    const int* __restrict__ faces_l,     // [N_FACES][3]
    const int* __restrict__ faces_r,
    float* __restrict__ partial)         // [NB][2][NCHUNK]
{
    const int b   = blockIdx.x;
    const int dir = blockIdx.y;
    const int z   = blockIdx.z;
    const int tid = threadIdx.x;
    const int lp  = tid >> 4;           // point-pair 0..15
    const int k   = tid & 15;           // split lane 0..15
    const int p0  = z * PCHUNK + lp;    // always < 251
    const int p1  = p0 + 16;            // may be >= 251 (invalid)
    const bool valid1 = (p1 < NPTS);

    __shared__ F3     sov[NPTS_PAD];    // other-hand verts (3072 B)
    __shared__ float4 st0[FPAD];        // face vertex arrays (24 KB)
    __shared__ float4 st1[FPAD];
    __shared__ float4 st2[FPAD];
    __shared__ F3     spts[PCHUNK];
    __shared__ float  wave_part[4];

    const float* vb = verts + (size_t)b * V_FULL * 3;
    const int* pind  = (dir == 0) ? inds_l  : inds_r;
    const int* oind  = (dir == 0) ? inds_r  : inds_l;
    const int* ploop = (dir == 0) ? loop_l  : loop_r;
    const int* oloop = (dir == 0) ? loop_r  : loop_l;
    const int* fcs   = (dir == 0) ? faces_r : faces_l;

    // Phase 1: gather other-hand verts (+pad) and this block's 32 points
    {
        int i = tid;  // 256 threads cover NPTS_PAD in one pass
        int go = (i < V_HAND) ? oind[i] : oind[0];   // pad = vertex 0 copy
        F3 v;
        v.x = vb[go * 3 + 0]; v.y = vb[go * 3 + 1]; v.z = vb[go * 3 + 2];
        if (i != V_HAND) sov[i] = v;                 // slot 250 = mean, below
    }
    if (tid == 0) {  // appended mean vertex of other hand
        float sx = 0.f, sy = 0.f, sz = 0.f;
        for (int i = 0; i < V_LOOP; ++i) {
            int gi = oloop[i];
            sx += vb[gi * 3 + 0]; sy += vb[gi * 3 + 1]; sz += vb[gi * 3 + 2];
        }
        const float inv = 1.0f / (float)V_LOOP;
        sov[V_HAND].x = sx * inv; sov[V_HAND].y = sy * inv; sov[V_HAND].z = sz * inv;
    }
    if (tid >= 64 && tid < 64 + PCHUNK) {
        int myp = z * PCHUNK + (tid - 64);
        F3 q = {0.f, 0.f, 0.f};
        if (myp < V_HAND) {
            int gp = pind[myp];
            q.x = vb[gp * 3 + 0]; q.y = vb[gp * 3 + 1]; q.z = vb[gp * 3 + 2];
        } else if (myp == V_HAND) {
            float sx = 0.f, sy = 0.f, sz = 0.f;
            for (int i = 0; i < V_LOOP; ++i) {
                int gi = ploop[i];
                sx += vb[gi * 3 + 0]; sy += vb[gi * 3 + 1]; sz += vb[gi * 3 + 2];
            }
            const float inv = 1.0f / (float)V_LOOP;
            q.x = sx * inv; q.y = sy * inv; q.z = sz * inv;
        }
        spts[tid - 64] = q;
    }
    __syncthreads();

    // Phase 2: build per-face float4 triangle arrays. Pad faces degenerate.
    for (int i = tid; i < FPAD; i += 256) {
        float4 v0, v1, v2;
        if (i < N_FACES) {
            int i0 = fcs[3 * i + 0], i1 = fcs[3 * i + 1], i2 = fcs[3 * i + 2];
            F3 a = sov[i0], bq = sov[i1], c = sov[i2];
            v0 = make_float4(a.x, a.y, a.z, 0.f);
            v1 = make_float4(bq.x, bq.y, bq.z, 0.f);
            v2 = make_float4(c.x, c.y, c.z, 0.f);
        } else {
            F3 a = sov[0];
            v0 = v1 = v2 = make_float4(a.x, a.y, a.z, 0.f);
        }
        st0[i] = v0; st1[i] = v1; st2[i] = v2;
    }
    __syncthreads();

    const float px0 = spts[lp].x,      py0 = spts[lp].y,      pz0 = spts[lp].z;
    const float px1 = spts[lp + 16].x, py1 = spts[lp + 16].y, pz1 = spts[lp + 16].z;

    // Winding partial sums: 32 uniform iterations, 3 b128 loads shared by
    // two independent point computations (ILP-2).
    float wsum0 = 0.0f, wsum1 = 0.0f;
    for (int f = k; f < FPAD; f += KSPLIT) {
        float4 va  = st0[f];
        float4 vb4 = st1[f];
        float4 vc  = st2[f];
        wsum0 += tri_omega(va, vb4, vc, px0, py0, pz0);
        wsum1 += tri_omega(va, vb4, vc, px1, py1, pz1);
    }

    // Min-dist partials: 16 uniform iterations, vertex load shared
    float d2min0 = 1e30f, d2min1 = 1e30f;
    for (int j = k; j < NPTS_PAD; j += KSPLIT) {
        F3 v = sov[j];
        float dx0 = v.x - px0, dy0 = v.y - py0, dz0 = v.z - pz0;
        float dx1 = v.x - px1, dy1 = v.y - py1, dz1 = v.z - pz1;
        d2min0 = fminf(d2min0, dx0 * dx0 + dy0 * dy0 + dz0 * dz0);
        d2min1 = fminf(d2min1, dx1 * dx1 + dy1 * dy1 + dz1 * dz1);
    }

    // Reduce across the 16-lane group (wave-aligned)
    wsum0 += __shfl_xor(wsum0, 1);  wsum1 += __shfl_xor(wsum1, 1);
    wsum0 += __shfl_xor(wsum0, 2);  wsum1 += __shfl_xor(wsum1, 2);
    wsum0 += __shfl_xor(wsum0, 4);  wsum1 += __shfl_xor(wsum1, 4);
    wsum0 += __shfl_xor(wsum0, 8);  wsum1 += __shfl_xor(wsum1, 8);
    d2min0 = fminf(d2min0, __shfl_xor(d2min0, 1));
    d2min0 = fminf(d2min0, __shfl_xor(d2min0, 2));
    d2min0 = fminf(d2min0, __shfl_xor(d2min0, 4));
    d2min0 = fminf(d2min0, __shfl_xor(d2min0, 8));
    d2min1 = fminf(d2min1, __shfl_xor(d2min1, 1));
    d2min1 = fminf(d2min1, __shfl_xor(d2min1, 2));
    d2min1 = fminf(d2min1, __shfl_xor(d2min1, 4));
    d2min1 = fminf(d2min1, __shfl_xor(d2min1, 8));

    float contrib = 0.0f;
    if (k == 0) {
        if (wsum0 > (float)M_PI)
            contrib += __builtin_amdgcn_sqrtf(d2min0 + 1e-12f);
        if (valid1 && wsum1 > (float)M_PI)
            contrib += __builtin_amdgcn_sqrtf(d2min1 + 1e-12f);
    }

    // Block reduction: wave64 shuffle then 4 partials in LDS
    for (int off = 32; off > 0; off >>= 1)
        contrib += __shfl_down(contrib, off);
    if ((tid & 63) == 0) wave_part[tid >> 6] = contrib;
    __syncthreads();
    if (tid == 0)
        partial[(b * 2 + dir) * NCHUNK + z] =
            wave_part[0] + wave_part[1] + wave_part[2] + wave_part[3];
}

__global__ void combine_kernel(const float* __restrict__ partial, float* __restrict__ out)
{
    int i = threadIdx.x;
    if (i < NB) {
        float s = 0.0f;
        for (int j = 0; j < 2 * NCHUNK; ++j)
            s += partial[i * 2 * NCHUNK + j];
        out[i] = s;
    }
}

extern "C" void kernel_launch(void* const* d_in, const int* in_sizes, int n_in,
                              void* d_out, int out_size, void* d_ws, size_t ws_size,
                              hipStream_t stream) {
    const float* verts  = (const float*)d_in[0];
    const int* inds_l   = (const int*)d_in[1];
    const int* inds_r   = (const int*)d_in[2];
    const int* loop_l   = (const int*)d_in[3];
    const int* loop_r   = (const int*)d_in[4];
    const int* faces_l  = (const int*)d_in[5];
    const int* faces_r  = (const int*)d_in[6];
    float* out = (float*)d_out;
    float* partial = (float*)d_ws;  // NB*2*NCHUNK floats

    hand_pen_kernel<<<dim3(NB, 2, NCHUNK), 256, 0, stream>>>(
        verts, inds_l, inds_r, loop_l, loop_r, faces_l, faces_r, partial);
    combine_kernel<<<1, 64, 0, stream>>>(partial, out);
}

// Round 8
// 40.585 us; speedup vs baseline: 1.3134x; 1.0039x over previous
//
#include <hip/hip_runtime.h>
#include <math.h>

#define NB 64
#define V_FULL 6890
#define V_HAND 250
#define V_LOOP 20
#define N_FACES 500
#define FPAD 512      // faces padded with degenerate (v0,v0,v0) -> omega = 0
#define NPTS 251      // V_HAND + 1 (appended loop-mean vertex)
#define NPTS_PAD 256  // min-dist pad (duplicates of vertex 0)
#define KSPLIT 32     // lanes per point-quad (face-loop split)
#define PCHUNK 32     // points per block (4 per thread)
#define NCHUNK 8      // 256 / PCHUNK

struct F3 { float x, y, z; };

// Branchless fast atan2. Range split decided BEFORE division (one rcp):
// hi <=> mn/mx > tan(pi/8). Poly max err ~3e-7 rad. atan2(0,0) -> 0.
__device__ __forceinline__ float fast_atan2f(float y, float x) {
    const float PI   = 3.14159265358979f;
    const float PIO2 = 1.57079632679490f;
    const float PIO4 = 0.78539816339745f;
    float ay = __builtin_fabsf(y), ax = __builtin_fabsf(x);
    float mx = fmaxf(ax, ay), mn = fminf(ax, ay);
    bool  hi = mn > 0.4142135624f * mx;
    float num = hi ? (mn - mx) : mn;
    float den = hi ? (mn + mx) : mx;
    float z  = num * __builtin_amdgcn_rcpf(fmaxf(den, 1e-38f));
    float z2 = z * z;
    float p  = fmaf(8.05374449538e-2f, z2, -1.38776856032e-1f);
    p = fmaf(p, z2, 1.99777106478e-1f);
    p = fmaf(p, z2, -3.33329491539e-1f);
    float r = fmaf(z2 * z, p, z);
    r += hi ? PIO4 : 0.0f;
    if (ay > ax)  r = PIO2 - r;
    if (x < 0.0f) r = PI - r;
    return copysignf(r, y);
}

// Solid-angle contribution of one triangle (va,vb,vc) seen from point p.
__device__ __forceinline__ float tri_omega(float4 va, float4 vb4, float4 vc,
                                           float px, float py, float pz) {
    float ax = va.x - px,  ay = va.y - py,  az = va.z - pz;
    float bx = vb4.x - px, by = vb4.y - py, bz = vb4.z - pz;
    float cx = vc.x - px,  cy = vc.y - py,  cz = vc.z - pz;

    float la = __builtin_amdgcn_sqrtf(ax * ax + ay * ay + az * az);
    float lb = __builtin_amdgcn_sqrtf(bx * bx + by * by + bz * bz);
    float lc = __builtin_amdgcn_sqrtf(cx * cx + cy * cy + cz * cz);

    float ux = by * cz - bz * cy;
    float uy = bz * cx - bx * cz;
    float uz = bx * cy - by * cx;
    float det = ax * ux + ay * uy + az * uz;

    float ab = ax * bx + ay * by + az * bz;
    float bc = bx * cx + by * cy + bz * cz;
    float ca = cx * ax + cy * ay + cz * az;

    float denom = fmaf(la, lb, ab) * lc + bc * la + ca * lb;
    return fast_atan2f(det, denom);
}

// Grid (NB, 2, NCHUNK). Block 256 = 8 point-quads x KSPLIT(32) lanes.
// Thread (quad q, lane k) owns points q, q+8, q+16, q+24 of its 32-point
// chunk (ILP-4; face loads amortized over 4 points).
__global__ __launch_bounds__(256) void hand_pen_kernel(
    const float* __restrict__ verts,     // [NB][V_FULL][3]
    const int* __restrict__ inds_l,
    const int* __restrict__ inds_r,
    const int* __restrict__ loop_l,
    const int* __restrict__ loop_r,
    const int* __restrict__ faces_l,     // [N_FACES][3]
    const int* __restrict__ faces_r,
    float* __restrict__ partial)         // [NB][2][NCHUNK]
{
    const int b   = blockIdx.x;
    const int dir = blockIdx.y;
    const int z   = blockIdx.z;
    const int tid = threadIdx.x;
    const int q   = tid >> 5;           // point-quad 0..7
    const int k   = tid & 31;           // split lane 0..31

    __shared__ float4 sov[NPTS_PAD];    // other-hand verts (4 KB, b128 reads)
    __shared__ float4 st0[FPAD];        // face vertex arrays (24 KB)
    __shared__ float4 st1[FPAD];
    __shared__ float4 st2[FPAD];
    __shared__ F3     spts[PCHUNK];
    __shared__ float  wave_part[4];

    const float* vb = verts + (size_t)b * V_FULL * 3;
    const int* pind  = (dir == 0) ? inds_l  : inds_r;
    const int* oind  = (dir == 0) ? inds_r  : inds_l;
    const int* ploop = (dir == 0) ? loop_l  : loop_r;
    const int* oloop = (dir == 0) ? loop_r  : loop_l;
    const int* fcs   = (dir == 0) ? faces_r : faces_l;

    // Phase 1: gather other-hand verts (+pad) and this block's 32 points
    {
        int i = tid;  // 256 threads cover NPTS_PAD in one pass
        int go = (i < V_HAND) ? oind[i] : oind[0];   // pad = vertex 0 copy
        float4 v = make_float4(vb[go * 3 + 0], vb[go * 3 + 1], vb[go * 3 + 2], 0.f);
        if (i != V_HAND) sov[i] = v;                 // slot 250 = mean, below
    }
    if (tid == 0) {  // appended mean vertex of other hand
        float sx = 0.f, sy = 0.f, sz = 0.f;
        for (int i = 0; i < V_LOOP; ++i) {
            int gi = oloop[i];
            sx += vb[gi * 3 + 0]; sy += vb[gi * 3 + 1]; sz += vb[gi * 3 + 2];
        }
        const float inv = 1.0f / (float)V_LOOP;
        sov[V_HAND] = make_float4(sx * inv, sy * inv, sz * inv, 0.f);
    }
    if (tid >= 64 && tid < 64 + PCHUNK) {
        int myp = z * PCHUNK + (tid - 64);
        F3 qv = {0.f, 0.f, 0.f};
        if (myp < V_HAND) {
            int gp = pind[myp];
            qv.x = vb[gp * 3 + 0]; qv.y = vb[gp * 3 + 1]; qv.z = vb[gp * 3 + 2];
        } else if (myp == V_HAND) {
            float sx = 0.f, sy = 0.f, sz = 0.f;
            for (int i = 0; i < V_LOOP; ++i) {
                int gi = ploop[i];
                sx += vb[gi * 3 + 0]; sy += vb[gi * 3 + 1]; sz += vb[gi * 3 + 2];
            }
            const float inv = 1.0f / (float)V_LOOP;
            qv.x = sx * inv; qv.y = sy * inv; qv.z = sz * inv;
        }
        spts[tid - 64] = qv;
    }
    __syncthreads();

    // Phase 2: build per-face float4 triangle arrays. Pad faces degenerate.
    for (int i = tid; i < FPAD; i += 256) {
        float4 v0, v1, v2;
        if (i < N_FACES) {
            int i0 = fcs[3 * i + 0], i1 = fcs[3 * i + 1], i2 = fcs[3 * i + 2];
            v0 = sov[i0]; v1 = sov[i1]; v2 = sov[i2];
        } else {
            v0 = v1 = v2 = sov[0];
        }
        st0[i] = v0; st1[i] = v1; st2[i] = v2;
    }
    __syncthreads();

    // This thread's 4 points: q, q+8, q+16, q+24 (global: + z*32)
    const float px0 = spts[q].x,      py0 = spts[q].y,      pz0 = spts[q].z;
    const float px1 = spts[q + 8].x,  py1 = spts[q + 8].y,  pz1 = spts[q + 8].z;
    const float px2 = spts[q + 16].x, py2 = spts[q + 16].y, pz2 = spts[q + 16].z;
    const float px3 = spts[q + 24].x, py3 = spts[q + 24].y, pz3 = spts[q + 24].z;
    const int p0 = z * PCHUNK + q;

    // Winding partial sums: 16 uniform iterations, 3 b128 loads shared by
    // four independent point computations (ILP-4).
    float ws0 = 0.f, ws1 = 0.f, ws2 = 0.f, ws3 = 0.f;
    for (int f = k; f < FPAD; f += KSPLIT) {
        float4 va  = st0[f];
        float4 vb4 = st1[f];
        float4 vc  = st2[f];
        ws0 += tri_omega(va, vb4, vc, px0, py0, pz0);
        ws1 += tri_omega(va, vb4, vc, px1, py1, pz1);
        ws2 += tri_omega(va, vb4, vc, px2, py2, pz2);
        ws3 += tri_omega(va, vb4, vc, px3, py3, pz3);
    }

    // Min-dist partials: 8 uniform iterations, b128 vertex load shared
    float d0 = 1e30f, d1 = 1e30f, d2m = 1e30f, d3 = 1e30f;
    for (int j = k; j < NPTS_PAD; j += KSPLIT) {
        float4 v = sov[j];
        float dx, dy, dz;
        dx = v.x - px0; dy = v.y - py0; dz = v.z - pz0;
        d0 = fminf(d0, dx * dx + dy * dy + dz * dz);
        dx = v.x - px1; dy = v.y - py1; dz = v.z - pz1;
        d1 = fminf(d1, dx * dx + dy * dy + dz * dz);
        dx = v.x - px2; dy = v.y - py2; dz = v.z - pz2;
        d2m = fminf(d2m, dx * dx + dy * dy + dz * dz);
        dx = v.x - px3; dy = v.y - py3; dz = v.z - pz3;
        d3 = fminf(d3, dx * dx + dy * dy + dz * dz);
    }

    // Reduce across the 32-lane group (xor <= 16 stays in wave half)
    #pragma unroll
    for (int off = 1; off <= 16; off <<= 1) {
        ws0 += __shfl_xor(ws0, off);
        ws1 += __shfl_xor(ws1, off);
        ws2 += __shfl_xor(ws2, off);
        ws3 += __shfl_xor(ws3, off);
        d0  = fminf(d0,  __shfl_xor(d0,  off));
        d1  = fminf(d1,  __shfl_xor(d1,  off));
        d2m = fminf(d2m, __shfl_xor(d2m, off));
        d3  = fminf(d3,  __shfl_xor(d3,  off));
    }

    float contrib = 0.0f;
    if (k == 0) {
        if (ws0 > (float)M_PI)
            contrib += __builtin_amdgcn_sqrtf(d0 + 1e-12f);
        if (ws1 > (float)M_PI)
            contrib += __builtin_amdgcn_sqrtf(d1 + 1e-12f);
        if (p0 + 16 < NPTS && ws2 > (float)M_PI)
            contrib += __builtin_amdgcn_sqrtf(d2m + 1e-12f);
        if (p0 + 24 < NPTS && ws3 > (float)M_PI)
            contrib += __builtin_amdgcn_sqrtf(d3 + 1e-12f);
    }

    // Block reduction: wave64 shuffle then 4 partials in LDS
    for (int off = 32; off > 0; off >>= 1)
        contrib += __shfl_down(contrib, off);
    if ((tid & 63) == 0) wave_part[tid >> 6] = contrib;
    __syncthreads();
    if (tid == 0)
        partial[(b * 2 + dir) * NCHUNK + z] =
            wave_part[0] + wave_part[1] + wave_part[2] + wave_part[3];
}

__global__ void combine_kernel(const float* __restrict__ partial, float* __restrict__ out)
{
    int i = threadIdx.x;
    if (i < NB) {
        float s = 0.0f;
        for (int j = 0; j < 2 * NCHUNK; ++j)
            s += partial[i * 2 * NCHUNK + j];
        out[i] = s;
    }
}

extern "C" void kernel_launch(void* const* d_in, const int* in_sizes, int n_in,
                              void* d_out, int out_size, void* d_ws, size_t ws_size,
                              hipStream_t stream) {
    const float* verts  = (const float*)d_in[0];
    const int* inds_l   = (const int*)d_in[1];
    const int* inds_r   = (const int*)d_in[2];
    const int* loop_l   = (const int*)d_in[3];
    const int* loop_r   = (const int*)d_in[4];
    const int* faces_l  = (const int*)d_in[5];
    const int* faces_r  = (const int*)d_in[6];
    float* out = (float*)d_out;
    float* partial = (float*)d_ws;  // NB*2*NCHUNK floats

    hand_pen_kernel<<<dim3(NB, 2, NCHUNK), 256, 0, stream>>>(
        verts, inds_l, inds_r, loop_l, loop_r, faces_l, faces_r, partial);
    combine_kernel<<<1, 64, 0, stream>>>(partial, out);
}